// Round 1
// baseline (672.160 us; speedup 1.0000x reference)
//
#include <hip/hip_runtime.h>
#include <math.h>

#define THREADS 256

// One block per row. Single pass: online softmax (m,d) + sum + sumsq,
// float4 coalesced loads, wave64 shuffle reduce, LDS combine, 1 atomic/row.
__global__ __launch_bounds__(THREADS) void newloss_kernel(
    const float* __restrict__ pred, const int* __restrict__ labels,
    float* __restrict__ out, int B, int C) {
  const int row = blockIdx.x;
  const int tid = threadIdx.x;
  const size_t base = (size_t)row * (size_t)C;
  const float4* __restrict__ p4 = (const float4*)(pred + base);
  const int n4 = C >> 2;

  float m = -INFINITY, d = 0.f, s = 0.f, ss = 0.f;

  for (int j = tid; j < n4; j += THREADS) {
    float4 x = p4[j];
    s  += (x.x + x.y) + (x.z + x.w);
    ss += (x.x * x.x + x.y * x.y) + (x.z * x.z + x.w * x.w);
    float vm = fmaxf(fmaxf(x.x, x.y), fmaxf(x.z, x.w));
    float nm = fmaxf(m, vm);
    d = d * __expf(m - nm)
      + __expf(x.x - nm) + __expf(x.y - nm)
      + __expf(x.z - nm) + __expf(x.w - nm);
    m = nm;
  }
  // scalar tail (not taken for C=32000, kept for generality)
  for (int j = (n4 << 2) + tid; j < C; j += THREADS) {
    float x = pred[base + j];
    s += x; ss += x * x;
    float nm = fmaxf(m, x);
    d = d * __expf(m - nm) + __expf(x - nm);
    m = nm;
  }

  // wave64 butterfly reduce: (m,d) softmax-merge; s,ss plain sums
  for (int off = 32; off > 0; off >>= 1) {
    float om  = __shfl_down(m, off);
    float od  = __shfl_down(d, off);
    float os  = __shfl_down(s, off);
    float oss = __shfl_down(ss, off);
    float nm = fmaxf(m, om);
    d = d * __expf(m - nm) + od * __expf(om - nm);
    m = nm;
    s += os; ss += oss;
  }

  __shared__ float sm[THREADS / 64], sd[THREADS / 64],
                   sv[THREADS / 64], sq[THREADS / 64];
  const int wave = tid >> 6;
  if ((tid & 63) == 0) { sm[wave] = m; sd[wave] = d; sv[wave] = s; sq[wave] = ss; }
  __syncthreads();

  if (tid == 0) {
    m = sm[0]; d = sd[0]; s = sv[0]; ss = sq[0];
    #pragma unroll
    for (int w = 1; w < THREADS / 64; ++w) {
      float om = sm[w], od = sd[w];
      float nm = fmaxf(m, om);
      d = d * __expf(m - nm) + od * __expf(om - nm);
      m = nm;
      s += sv[w]; ss += sq[w];
    }
    const int lbl = labels[row];
    const float tgt = pred[base + (size_t)lbl];
    const float lse = m + __logf(d);
    const float n = (float)(C - 1);
    const float s_ex  = s - tgt;
    const float ss_ex = ss - tgt * tgt;
    // A = 1.0, B_COEF = 0.005, ce uses mean over rows
    const float row_val = (lse - tgt) * (1.0f / (float)B)
                        + 0.005f * (ss_ex - (s_ex * s_ex) / n);
    atomicAdd(out, row_val);
  }
}

extern "C" void kernel_launch(void* const* d_in, const int* in_sizes, int n_in,
                              void* d_out, int out_size, void* d_ws, size_t ws_size,
                              hipStream_t stream) {
  const float* pred = (const float*)d_in[0];
  const int* labels = (const int*)d_in[1];
  float* out = (float*)d_out;
  const int B = in_sizes[1];
  const int C = in_sizes[0] / B;

  // d_out is re-poisoned to 0xAA before every launch — zero it (capture-safe).
  hipMemsetAsync(out, 0, sizeof(float), stream);
  newloss_kernel<<<B, THREADS, 0, stream>>>(pred, labels, out, B, C);
}